// Round 4
// baseline (26.353 us; speedup 1.0000x reference)
//
#include <hip/hip_runtime.h>

// Basket embedding mean-pool.
// item_ids: [B, L, M] int32; basket_lens: [B, L] int32; emb: [VOCAB, H] f32
// out: [B, L, H] f32 ; out[b,l,:] = sum_{m<len} emb[ids[b,l,m]] / max(len,1)
//
// R4: exec-masked gathers. R2/R3 loaded all 20 slots (padding -> dup id0
// fetches) which doubles L2/LLC gather traffic (~262 MB vs ~131 MB useful);
// table (25.6 MB) >> 4 MB L2/XCD so ~84% comes from LLC -> traffic-bound.
// `if (m < len) load` exec-masks inactive lanes: padded slots produce zero
// requests AND exact-zero values, so the accumulate is unconditional adds.

constexpr int Bn = 1024, Ln = 50, Mn = 20, Hn = 64;
constexpr int NB = Bn * Ln;                 // 51200 baskets
constexpr int RING = 8;

__global__ __launch_bounds__(256, 4) void basket_pool_kernel(
    const int* __restrict__ item_ids,       // [NB, M]
    const int* __restrict__ basket_lens,    // [NB]
    const float* __restrict__ emb,          // [VOCAB, H]
    float* __restrict__ out)                // [NB, H]
{
    const int tid    = blockIdx.x * blockDim.x + threadIdx.x;
    const int basket = tid >> 4;            // 16 lanes per basket
    const int lane4  = (tid & 15) << 2;     // h offset: lane*4
    if (basket >= NB) return;

    const int len = basket_lens[basket];
    const int* __restrict__ ids = item_ids + basket * Mn;

    // preload all 20 ids (5x int4, coalesced within each 16-lane group)
    int idb[Mn];
#pragma unroll
    for (int c = 0; c < Mn / 4; ++c) {
        const int4 t = reinterpret_cast<const int4*>(ids)[c];
        idb[c * 4 + 0] = t.x;
        idb[c * 4 + 1] = t.y;
        idb[c * 4 + 2] = t.z;
        idb[c * 4 + 3] = t.w;
    }

    // ring of in-flight gathers; m >= len slots are exec-masked (no traffic)
    float4 v[RING];
#pragma unroll
    for (int m = 0; m < RING; ++m) {
        float4 t = make_float4(0.f, 0.f, 0.f, 0.f);
        if (m < len)
            t = *reinterpret_cast<const float4*>(emb + (idb[m] * Hn + lane4));
        v[m] = t;
    }

    float4 acc0 = make_float4(0.f, 0.f, 0.f, 0.f);
    float4 acc1 = make_float4(0.f, 0.f, 0.f, 0.f);
#pragma unroll
    for (int m = 0; m < Mn; ++m) {
        const float4 x = v[m % RING];                     // consume
        if (m + RING < Mn) {                              // refill slot (masked)
            float4 t = make_float4(0.f, 0.f, 0.f, 0.f);
            if (m + RING < len)
                t = *reinterpret_cast<const float4*>(
                        emb + (idb[m + RING] * Hn + lane4));
            v[m % RING] = t;
        }
        if (m & 1) {
            acc1.x += x.x; acc1.y += x.y; acc1.z += x.z; acc1.w += x.w;
        } else {
            acc0.x += x.x; acc0.y += x.y; acc0.z += x.z; acc0.w += x.w;
        }
    }

    const float inv = 1.0f / (float)(len > 0 ? len : 1);
    float4 r;
    r.x = (acc0.x + acc1.x) * inv;
    r.y = (acc0.y + acc1.y) * inv;
    r.z = (acc0.z + acc1.z) * inv;
    r.w = (acc0.w + acc1.w) * inv;

    *reinterpret_cast<float4*>(out + (basket * Hn + lane4)) = r;
}

extern "C" void kernel_launch(void* const* d_in, const int* in_sizes, int n_in,
                              void* d_out, int out_size, void* d_ws, size_t ws_size,
                              hipStream_t stream) {
    const int*   item_ids    = (const int*)d_in[0];    // B*L*M
    const int*   basket_lens = (const int*)d_in[1];    // B*L
    const float* emb         = (const float*)d_in[2];  // VOCAB*H
    float*       out         = (float*)d_out;          // B*L*H

    const int total_threads = NB * 16;                 // 819200
    const int block = 256;
    const int grid  = (total_threads + block - 1) / block;  // 3200
    basket_pool_kernel<<<grid, block, 0, stream>>>(item_ids, basket_lens, emb, out);
}

// Round 5
// 24.738 us; speedup vs baseline: 1.0653x; 1.0653x over previous
//
#include <hip/hip_runtime.h>

// Basket embedding mean-pool.
// item_ids: [B, L, M] int32; basket_lens: [B, L] int32; emb: [VOCAB, H] f32
// out: [B, L, H] f32 ; out[b,l,:] = sum_{m<len} emb[ids[b,l,m]] / max(len,1)
//
// R5: lean burst-20. Decisive test of "per-wave in-flight depth" vs
// "per-CU outstanding-miss cap". All 20 byte-offsets precomputed (32-bit,
// SADDR+voffset form), then 20 back-to-back dwordx4 gathers in flight,
// then 4 independent accumulate chains. Padded slots re-load id0's line
// (MSHR-merged, proven ~free in R4 A/B). No launch_bounds cap.

constexpr int Bn = 1024, Ln = 50, Mn = 20, Hn = 64;
constexpr int NB = Bn * Ln;                 // 51200 baskets

__global__ void basket_pool_kernel(
    const int* __restrict__ item_ids,       // [NB, M]
    const int* __restrict__ basket_lens,    // [NB]
    const float* __restrict__ emb,          // [VOCAB, H]
    float* __restrict__ out)                // [NB, H]
{
    const int tid    = blockIdx.x * blockDim.x + threadIdx.x;
    const int basket = tid >> 4;            // 16 lanes per basket
    const int lane4  = (tid & 15) << 2;     // h offset: lane*4
    if (basket >= NB) return;

    const int len = basket_lens[basket];
    const int* __restrict__ ids = item_ids + basket * Mn;

    // preload all 20 ids (5x int4, coalesced within each 16-lane group)
    int idb[Mn];
#pragma unroll
    for (int c = 0; c < Mn / 4; ++c) {
        const int4 t = reinterpret_cast<const int4*>(ids)[c];
        idb[c * 4 + 0] = t.x;
        idb[c * 4 + 1] = t.y;
        idb[c * 4 + 2] = t.z;
        idb[c * 4 + 3] = t.w;
    }
    const int id0 = idb[0];

    // all 20 element-offsets up front (32-bit; idb dies here)
    int off[Mn];
#pragma unroll
    for (int m = 0; m < Mn; ++m) {
        const int e = (m < len) ? idb[m] : id0;   // dup slot -> MSHR-merge
        off[m] = e * Hn + lane4;
    }

    // 20 gathers back-to-back: maximum sustained per-wave depth
    float4 v[Mn];
#pragma unroll
    for (int m = 0; m < Mn; ++m)
        v[m] = *reinterpret_cast<const float4*>(emb + off[m]);

    // 4 independent accumulate chains, masked weights
    float4 a0 = make_float4(0.f, 0.f, 0.f, 0.f);
    float4 a1 = make_float4(0.f, 0.f, 0.f, 0.f);
    float4 a2 = make_float4(0.f, 0.f, 0.f, 0.f);
    float4 a3 = make_float4(0.f, 0.f, 0.f, 0.f);
#pragma unroll
    for (int m = 0; m < Mn; m += 4) {
        const float w0 = (m + 0 < len) ? 1.f : 0.f;
        const float w1 = (m + 1 < len) ? 1.f : 0.f;
        const float w2 = (m + 2 < len) ? 1.f : 0.f;
        const float w3 = (m + 3 < len) ? 1.f : 0.f;
        a0.x = fmaf(v[m + 0].x, w0, a0.x); a0.y = fmaf(v[m + 0].y, w0, a0.y);
        a0.z = fmaf(v[m + 0].z, w0, a0.z); a0.w = fmaf(v[m + 0].w, w0, a0.w);
        a1.x = fmaf(v[m + 1].x, w1, a1.x); a1.y = fmaf(v[m + 1].y, w1, a1.y);
        a1.z = fmaf(v[m + 1].z, w1, a1.z); a1.w = fmaf(v[m + 1].w, w1, a1.w);
        a2.x = fmaf(v[m + 2].x, w2, a2.x); a2.y = fmaf(v[m + 2].y, w2, a2.y);
        a2.z = fmaf(v[m + 2].z, w2, a2.z); a2.w = fmaf(v[m + 2].w, w2, a2.w);
        a3.x = fmaf(v[m + 3].x, w3, a3.x); a3.y = fmaf(v[m + 3].y, w3, a3.y);
        a3.z = fmaf(v[m + 3].z, w3, a3.z); a3.w = fmaf(v[m + 3].w, w3, a3.w);
    }

    const float inv = 1.0f / (float)(len > 0 ? len : 1);
    float4 r;
    r.x = (a0.x + a1.x + a2.x + a3.x) * inv;
    r.y = (a0.y + a1.y + a2.y + a3.y) * inv;
    r.z = (a0.z + a1.z + a2.z + a3.z) * inv;
    r.w = (a0.w + a1.w + a2.w + a3.w) * inv;

    *reinterpret_cast<float4*>(out + (basket * Hn + lane4)) = r;
}

extern "C" void kernel_launch(void* const* d_in, const int* in_sizes, int n_in,
                              void* d_out, int out_size, void* d_ws, size_t ws_size,
                              hipStream_t stream) {
    const int*   item_ids    = (const int*)d_in[0];    // B*L*M
    const int*   basket_lens = (const int*)d_in[1];    // B*L
    const float* emb         = (const float*)d_in[2];  // VOCAB*H
    float*       out         = (float*)d_out;          // B*L*H

    const int total_threads = NB * 16;                 // 819200
    const int block = 256;
    const int grid  = (total_threads + block - 1) / block;  // 3200
    basket_pool_kernel<<<grid, block, 0, stream>>>(item_ids, basket_lens, emb, out);
}